// Round 8
// baseline (255.169 us; speedup 1.0000x reference)
//
#include <hip/hip_runtime.h>

// RNN: o_t = tanh(relu([x_t, o_{t-1}] @ W1[t] + b1[t]) @ W2[t] + b2[t]), T=30.
// Round-8 design (r7 + critical-path polish) — RESUBMIT: round-7 bench died
// acquiring the MI355X container (infra, kernel never ran; same signature as
// round 1 which passed on resubmit).
//  - r7 post-mortem: j-pair packing cut busy 96->70us but VALUBusy fell to
//    70%: per-jj pk_fma(o2,wh,bb) reads TWO SGPR pairs (illegal in one VALU
//    op) -> compiler inserts v_movs (~20% issue tax); and the shorter step
//    exposes fixed latencies (LDS xv read ~120cy, 10-deep acc fma chain,
//    s_load at loop top).
//  - Fix 1 (mov tax): restructure so every op reads <=1 scalar constant:
//      p = pk_mul(x2,wx); p = pk_fma(o2,wh,p); p = pk_add(p,bb);
//      p = pk_max(p,0);   acc = pk_fma(p,w2,acc)   // 5 pk ops, 0 movs
//  - Fix 2 (acc chain): even-jj -> acc0, odd-jj -> acc1; halves the serial
//    fma chain; +1 pk_add at the end of the step.
//  - Fix 3 (LDS latency): prefetch xv[t+1] before the j-loop; tile padded to
//    31 rows so the t=29 prefetch is in-bounds (still 5 blocks/CU: 31x257x4
//    = 31868B -> 63x512B alloc, 5x = 161280 <= 163840).
//  - Fix 4 (s_load latency): #pragma unroll 2 on the t-loop so step t+1's
//    s_loads issue under step t's compute. Body ~600B -> no I$ risk (r6).
//  - Everything else r7-verbatim: M=1, EPB=256, ROW=257 (odd, bank-clean),
//    j-pair weights 10.5KB K$-resident, staging/gather transpose phases.

#define TS  30
#define HID 20
#define THR 256
#define EPB 256              // elements per block (M=1)
#define ROW 257              // LDS row stride in floats (odd -> bank-clean)
#define WST 44               // f2 slots per timestep in repacked weights

typedef float f2 __attribute__((ext_vector_type(2)));

__device__ __forceinline__ float fast_tanh(float y) {
    // tanh(y) = 1 - 2/(exp(2y)+1); correct saturation at +/-inf.
    float e = __expf(2.0f * y);
    return 1.0f - 2.0f * __builtin_amdgcn_rcpf(e + 1.0f);
}

// wp2[t*44 + s]: s in [0,10): {W1x[2s],W1x[2s+1]}
//               s in [10,20): {W1h[..]}   s in [20,30): {b1[..]}
//               s in [30,40): {W2[..]}    s == 40: {b2[t],0}; rest pad.
__global__ __launch_bounds__(256) void repack_w(
        const float* __restrict__ W1, const float* __restrict__ b1,
        const float* __restrict__ W2, const float* __restrict__ b2,
        f2* __restrict__ wp2) {
    for (int i = threadIdx.x; i < TS * WST; i += 256) {
        const int t = i / WST;
        const int s = i - t * WST;
        f2 v = {0.f, 0.f};
        if (s < 10) {
            const int j = 2 * s;
            v = (f2){W1[t * 40 + j], W1[t * 40 + j + 1]};
        } else if (s < 20) {
            const int j = 2 * (s - 10);
            v = (f2){W1[t * 40 + 20 + j], W1[t * 40 + 20 + j + 1]};
        } else if (s < 30) {
            const int j = 2 * (s - 20);
            v = (f2){b1[t * 20 + j], b1[t * 20 + j + 1]};
        } else if (s < 40) {
            const int j = 2 * (s - 30);
            v = (f2){W2[t * 20 + j], W2[t * 20 + j + 1]};
        } else if (s == 40) {
            v = (f2){b2[t], 0.f};
        }
        wp2[i] = v;
    }
}

__global__ __launch_bounds__(256, 5) void rnn8(
        const float* __restrict__ x,
        const f2* __restrict__ wp2,
        float* __restrict__ out) {
    __shared__ float tile[(TS + 1) * ROW];           // +1 pad row (prefetch)
    const int tid = threadIdx.x;
    const size_t gbase = (size_t)blockIdx.x * (EPB * TS);

    // ---- coalesced float2 load + LDS transpose scatter (r3/r7 verbatim) ----
    const float2* xg = reinterpret_cast<const float2*>(x + gbase);
#pragma unroll
    for (int i = 0; i < 15; ++i) {
        const float2 v = xg[i * THR + tid];
        const unsigned f0 = (unsigned)(i * THR + tid) * 2u;
        const unsigned e0 = (f0 * 34953u) >> 20;     // exact f/30 for f < 74898
        const unsigned t0 = f0 - e0 * 30u;
        tile[t0 * ROW + e0] = v.x;
        const unsigned f1 = f0 + 1u;
        const unsigned e1 = (f1 * 34953u) >> 20;
        const unsigned t1 = f1 - e1 * 30u;
        tile[t1 * ROW + e1] = v.y;
    }
    __syncthreads();

    // ---- recurrence: M=1, j-pairs packed, xv prefetched, dual acc ----
    float o = 0.f;
    float xv = tile[tid];                            // prefetch t=0
#pragma unroll 2
    for (int t = 0; t < TS; ++t) {
        const f2* wr = wp2 + t * WST;                // wave-uniform -> s_load
        const float xv_n = tile[(t + 1) * ROW + tid];  // prefetch t+1 (pad ok)
        const f2 x2 = {xv, xv};
        const f2 o2 = {o, o};
        f2 acc0 = {wr[40].x, 0.f};                   // b2 in one half
        f2 acc1 = {0.f, 0.f};
#pragma unroll
        for (int jj = 0; jj < 10; jj += 2) {
            {                                        // even jj -> acc0
                f2 p = x2 * wr[jj];                  // pk_mul   (1 SGPR)
                p = o2 * wr[10 + jj] + p;            // pk_fma   (1 SGPR)
                p = p + wr[20 + jj];                 // pk_add   (1 SGPR)
                p.x = __builtin_fmaxf(p.x, 0.f);
                p.y = __builtin_fmaxf(p.y, 0.f);     // pk_max
                acc0 = p * wr[30 + jj] + acc0;       // pk_fma   (1 SGPR)
            }
            {                                        // odd jj -> acc1
                f2 p = x2 * wr[jj + 1];
                p = o2 * wr[10 + jj + 1] + p;
                p = p + wr[20 + jj + 1];
                p.x = __builtin_fmaxf(p.x, 0.f);
                p.y = __builtin_fmaxf(p.y, 0.f);
                acc1 = p * wr[30 + jj + 1] + acc1;
            }
        }
        const f2 acc = acc0 + acc1;                  // pk_add
        o = fast_tanh(acc.x + acc.y);
        tile[t * ROW + tid] = o;                     // in-place: x -> o
        xv = xv_n;
    }
    __syncthreads();

    // ---- LDS gather + coalesced float2 store (r3/r7 verbatim) ----
    float2* og = reinterpret_cast<float2*>(out + gbase);
#pragma unroll
    for (int i = 0; i < 15; ++i) {
        const unsigned f0 = (unsigned)(i * THR + tid) * 2u;
        const unsigned e0 = (f0 * 34953u) >> 20;
        const unsigned t0 = f0 - e0 * 30u;
        const unsigned f1 = f0 + 1u;
        const unsigned e1 = (f1 * 34953u) >> 20;
        const unsigned t1 = f1 - e1 * 30u;
        float2 v;
        v.x = tile[t0 * ROW + e0];
        v.y = tile[t1 * ROW + e1];
        og[i * THR + tid] = v;
    }
}

extern "C" void kernel_launch(void* const* d_in, const int* in_sizes, int n_in,
                              void* d_out, int out_size, void* d_ws, size_t ws_size,
                              hipStream_t stream) {
    const float* x  = (const float*)d_in[0];
    const float* W1 = (const float*)d_in[1];
    const float* b1 = (const float*)d_in[2];
    const float* W2 = (const float*)d_in[3];
    const float* b2 = (const float*)d_in[4];
    float* out = (float*)d_out;
    f2* wp2 = (f2*)d_ws;                             // 30*44*8 = 10560 B

    repack_w<<<1, 256, 0, stream>>>(W1, b1, W2, b2, wp2);

    const int B = 1048576;
    const int grid = B / EPB;                        // 4096 blocks
    rnn8<<<grid, 256, 0, stream>>>(x, wp2, out);
}